// Round 5
// baseline (765.190 us; speedup 1.0000x reference)
//
#include <hip/hip_runtime.h>
#include <hip/hip_bf16.h>

#define T_TOK 4096
#define D_MODEL 1024
#define I_DIM 2048
#define E_EXP 16

typedef __bf16 bf16x8 __attribute__((ext_vector_type(8)));
typedef float f32x4 __attribute__((ext_vector_type(4)));

__device__ __forceinline__ bf16x8 pack8(f32x4 a, f32x4 b) {
    bf16x8 r;
    r[0] = (__bf16)a[0]; r[1] = (__bf16)a[1]; r[2] = (__bf16)a[2]; r[3] = (__bf16)a[3];
    r[4] = (__bf16)b[0]; r[5] = (__bf16)b[1]; r[6] = (__bf16)b[2]; r[7] = (__bf16)b[3];
    return r;
}

__device__ __forceinline__ void gl2lds(const __bf16* src, __bf16* dst) {
    __builtin_amdgcn_global_load_lds(
        (const __attribute__((address_space(1))) unsigned int*)src,
        (__attribute__((address_space(3))) unsigned int*)dst, 16, 0, 0);
}

__global__ __launch_bounds__(256) void cvt_kernel(
    const float* __restrict__ in, __bf16* __restrict__ out, int n8)
{
    const int stride = gridDim.x * 256;
    for (int i = blockIdx.x * 256 + threadIdx.x; i < n8; i += stride) {
        f32x4 a = ((const f32x4*)in)[i * 2];
        f32x4 b = ((const f32x4*)in)[i * 2 + 1];
        ((bf16x8*)out)[i] = pack8(a, b);
    }
}

// ---------------- Router: fp64-accum logits, top-4, softmax-over-top4 ----------------
__global__ __launch_bounds__(256) void router_kernel(
    const float* __restrict__ x, const float* __restrict__ rw,
    int* __restrict__ counts, int* __restrict__ tok_list, float* __restrict__ gate_list)
{
    const int wid = threadIdx.x >> 6, lane = threadIdx.x & 63;
    const int t = blockIdx.x * 4 + wid;
    const int e = lane & 15, part = lane >> 4;

    const float* xr = x + (size_t)t * D_MODEL + part * 256;
    const float* wr = rw + (size_t)e * D_MODEL + part * 256;
    double acc = 0.0;
    #pragma unroll 4
    for (int i = 0; i < 256; i += 4) {
        f32x4 xv = *(const f32x4*)(xr + i);
        f32x4 wv = *(const f32x4*)(wr + i);
        acc += (double)xv[0] * wv[0] + (double)xv[1] * wv[1]
             + (double)xv[2] * wv[2] + (double)xv[3] * wv[3];
    }
    acc += __shfl_xor(acc, 16, 64);
    acc += __shfl_xor(acc, 32, 64);

    __shared__ float logits[4][16];
    if (lane < 16) logits[wid][lane] = (float)acc;
    __syncthreads();

    if (lane == 0) {
        float l[16];
        #pragma unroll
        for (int i = 0; i < 16; i++) l[i] = logits[wid][i];
        int idx[4]; float val[4];
        unsigned taken = 0;
        for (int k = 0; k < 4; k++) {
            int best = 0; float bv = -1e30f;
            for (int i = 0; i < 16; i++)
                if (!((taken >> i) & 1) && l[i] > bv) { bv = l[i]; best = i; }
            idx[k] = best; val[k] = bv; taken |= (1u << best);
        }
        float m = val[0];
        float w[4], s = 0.f;
        for (int k = 0; k < 4; k++) { w[k] = __expf(val[k] - m); s += w[k]; }
        for (int k = 0; k < 4; k++) {
            int ee = idx[k];
            int slot = atomicAdd(&counts[ee], 1);
            tok_list[ee * T_TOK + slot] = t;
            gate_list[ee * T_TOK + slot] = w[k] / s;
        }
    }
}

__global__ void prefix_kernel(const int* __restrict__ counts, int* __restrict__ prefix) {
    if (threadIdx.x == 0) {
        int acc = 0;
        for (int e = 0; e < E_EXP; e++) { prefix[e] = acc; acc += (counts[e] + 255) & ~255; }
        prefix[E_EXP] = acc;
    }
}

// ======================= GEMM1 + SwiGLU =======================
// 256 tok x 256 B-rows, BK=32, 8 waves (2M x 4N), 3-buffer rotation staged 2
// tiles ahead, ONE barrier per K-tile, counted vmcnt (never 0 in loop).
// 4-chunk XOR swizzle (involution) on gl_lds SOURCE addr + ds_read addr.
// XCD-chunked 1D grid: each expert's 128 blocks consecutive on one XCD.
__global__ __launch_bounds__(512) void gemm1_kernel(
    const __bf16* __restrict__ xb, const __bf16* __restrict__ wsb,
    const int* __restrict__ counts, const int* __restrict__ prefix,
    const int* __restrict__ tok_list, __bf16* __restrict__ act)
{
    const int q8 = gridDim.x >> 3;
    const int lid = (blockIdx.x & 7) * q8 + (blockIdx.x >> 3);
    const int e = lid >> 7;
    const int r = lid & 127;
    const int tileM = r & 7;
    const int tileN = r >> 3;

    const int count = counts[e];
    if (tileM * 256 >= count) return;

    const int tid = threadIdx.x;
    const int lane = tid & 63, w = tid >> 6;
    const int l15 = lane & 15, q = lane >> 4;
    const int wm = w >> 2, wn = w & 3;

    __shared__ __bf16 As[3][256 * 32];
    __shared__ __bf16 Bs[3][256 * 32];

    // staging: issue i covers 16 rows (w-region row i*16 + (lane>>2)), phys chunk lane&3
    const int rl = lane >> 2;                       // row within 16-row issue group
    const int lc = (lane & 3) ^ (rl & 3);           // logical chunk (involution)
    const __bf16* ptr[4];
    if (w < 4) {
        #pragma unroll
        for (int i = 0; i < 4; ++i) {
            int grow = tileM * 256 + w * 64 + i * 16 + rl;
            if (grow >= count) grow = count - 1;
            const int token = tok_list[e * T_TOK + grow];
            ptr[i] = xb + (size_t)token * D_MODEL + lc * 8;
        }
    } else {
        const int w4 = w - 4;
        #pragma unroll
        for (int i = 0; i < 4; ++i) {
            const int sub = i * 16 + rl;
            const int gcol = (sub < 32) ? (tileN * 128 + w4 * 32 + sub)
                                        : (I_DIM + tileN * 128 + w4 * 32 + (sub - 32));
            ptr[i] = wsb + ((size_t)e * 2 * I_DIM + gcol) * D_MODEL + lc * 8;
        }
    }
    const int wreg = (w & 3) * 2048;   // wave's 64-row LDS slice (64*32 elems)
    __bf16* baseAB = (w < 4) ? &As[0][wreg] : &Bs[0][wreg];

    #define STAGE(bufi, koff) do { \
        __bf16* d_ = baseAB + (bufi) * 8192; \
        _Pragma("unroll") \
        for (int i_ = 0; i_ < 4; ++i_) gl2lds(ptr[i_] + (koff), d_ + i_ * 512); \
    } while (0)

    f32x4 acc[8][4];
    const f32x4 z = {0.f, 0.f, 0.f, 0.f};
    #pragma unroll
    for (int mi = 0; mi < 8; ++mi)
        #pragma unroll
        for (int nj = 0; nj < 4; ++nj) acc[mi][nj] = z;

    // read offsets: row*32 + (q ^ (row&3))*8 ; row&3 == l15&3 for all frags
    const int rc = (q ^ (l15 & 3)) * 8;
    const int aoff = (wm * 128 + l15) * 32 + rc;    // + mi*512
    const int boff = (wn * 64 + l15) * 32 + rc;     // + nj*512

    STAGE(0, 0);
    STAGE(1, 32);
    int b0 = 0, b1 = 1, b2 = 2;
    for (int kt = 0; kt < 32; ++kt) {
        if (kt < 31) asm volatile("s_waitcnt vmcnt(4)" ::: "memory");
        else         asm volatile("s_waitcnt vmcnt(0)" ::: "memory");
        __builtin_amdgcn_s_barrier();
        asm volatile("" ::: "memory");
        if (kt < 30) STAGE(b2, (kt + 2) * 32);
        const __bf16* Ab = As[b0];
        const __bf16* Bb = Bs[b0];
        bf16x8 a[8], b[4];
        #pragma unroll
        for (int nj = 0; nj < 4; ++nj) b[nj] = *(const bf16x8*)&Bb[boff + nj * 512];
        #pragma unroll
        for (int mi = 0; mi < 8; ++mi) a[mi] = *(const bf16x8*)&Ab[aoff + mi * 512];
        __builtin_amdgcn_s_setprio(1);
        #pragma unroll
        for (int mi = 0; mi < 8; ++mi)
            #pragma unroll
            for (int nj = 0; nj < 4; ++nj)
                acc[mi][nj] = __builtin_amdgcn_mfma_f32_16x16x32_bf16(a[mi], b[nj], acc[mi][nj], 0, 0, 0);
        __builtin_amdgcn_s_setprio(0);
        const int t_ = b0; b0 = b1; b1 = b2; b2 = t_;
    }
    #undef STAGE

    const int abase = prefix[e];
    #pragma unroll
    for (int mi = 0; mi < 8; ++mi) {
        #pragma unroll
        for (int j = 0; j < 4; ++j) {
            const int grow = tileM * 256 + wm * 128 + mi * 16 + q * 4 + j;
            if (grow < count) {
                __bf16* arowp = act + (size_t)(abase + grow) * I_DIM + tileN * 128 + wn * 32 + l15;
                #pragma unroll
                for (int nj = 0; nj < 2; ++nj) {
                    const float v1 = acc[mi][nj][j];
                    const float v2 = acc[mi][nj + 2][j];
                    arowp[nj * 16] = (__bf16)(v1 / (1.f + __expf(-v1)) * v2);
                }
            }
        }
    }
}

// ======================= GEMM2 =======================
// 256 rows x 256 d-cols, K split in 2 halves of 1024 (h), BK=32, same 3-buffer
// pipeline; epilogue scatters gate*y with fp32 atomics. XCD-chunked 1D grid.
__global__ __launch_bounds__(512) void gemm2_kernel(
    const __bf16* __restrict__ act, const __bf16* __restrict__ w2b,
    const int* __restrict__ counts, const int* __restrict__ prefix,
    const int* __restrict__ tok_list, const float* __restrict__ gate_list,
    float* __restrict__ out)
{
    const int q8 = gridDim.x >> 3;
    const int lid = (blockIdx.x & 7) * q8 + (blockIdx.x >> 3);
    const int e = lid >> 6;
    const int r = lid & 63;
    const int h = r >> 5;
    const int rr = r & 31;
    const int tileM = rr & 7;
    const int tileN = rr >> 3;

    const int count = counts[e];
    if (tileM * 256 >= count) return;

    const int tid = threadIdx.x;
    const int lane = tid & 63, w = tid >> 6;
    const int l15 = lane & 15, q = lane >> 4;
    const int wm = w >> 2, wn = w & 3;
    const int abase = prefix[e];

    __shared__ __bf16 As[3][256 * 32];
    __shared__ __bf16 Bs[3][256 * 32];

    const int rl = lane >> 2;
    const int lc = (lane & 3) ^ (rl & 3);
    const __bf16* ptr[4];
    if (w < 4) {
        #pragma unroll
        for (int i = 0; i < 4; ++i) {
            const int rw_ = tileM * 256 + w * 64 + i * 16 + rl;   // padded rows exist in act
            ptr[i] = act + (size_t)(abase + rw_) * I_DIM + h * 1024 + lc * 8;
        }
    } else {
        const int w4 = w - 4;
        #pragma unroll
        for (int i = 0; i < 4; ++i) {
            const int dcol = tileN * 256 + w4 * 64 + i * 16 + rl;
            ptr[i] = w2b + ((size_t)e * D_MODEL + dcol) * I_DIM + h * 1024 + lc * 8;
        }
    }
    const int wreg = (w & 3) * 2048;
    __bf16* baseAB = (w < 4) ? &As[0][wreg] : &Bs[0][wreg];

    #define STAGE(bufi, koff) do { \
        __bf16* d_ = baseAB + (bufi) * 8192; \
        _Pragma("unroll") \
        for (int i_ = 0; i_ < 4; ++i_) gl2lds(ptr[i_] + (koff), d_ + i_ * 512); \
    } while (0)

    f32x4 acc[8][4];
    const f32x4 z = {0.f, 0.f, 0.f, 0.f};
    #pragma unroll
    for (int mi = 0; mi < 8; ++mi)
        #pragma unroll
        for (int nj = 0; nj < 4; ++nj) acc[mi][nj] = z;

    const int rc = (q ^ (l15 & 3)) * 8;
    const int aoff = (wm * 128 + l15) * 32 + rc;
    const int boff = (wn * 64 + l15) * 32 + rc;

    STAGE(0, 0);
    STAGE(1, 32);
    int b0 = 0, b1 = 1, b2 = 2;
    for (int kt = 0; kt < 32; ++kt) {
        if (kt < 31) asm volatile("s_waitcnt vmcnt(4)" ::: "memory");
        else         asm volatile("s_waitcnt vmcnt(0)" ::: "memory");
        __builtin_amdgcn_s_barrier();
        asm volatile("" ::: "memory");
        if (kt < 30) STAGE(b2, (kt + 2) * 32);
        const __bf16* Ab = As[b0];
        const __bf16* Bb = Bs[b0];
        bf16x8 a[8], b[4];
        #pragma unroll
        for (int nj = 0; nj < 4; ++nj) b[nj] = *(const bf16x8*)&Bb[boff + nj * 512];
        #pragma unroll
        for (int mi = 0; mi < 8; ++mi) a[mi] = *(const bf16x8*)&Ab[aoff + mi * 512];
        __builtin_amdgcn_s_setprio(1);
        #pragma unroll
        for (int mi = 0; mi < 8; ++mi)
            #pragma unroll
            for (int nj = 0; nj < 4; ++nj)
                acc[mi][nj] = __builtin_amdgcn_mfma_f32_16x16x32_bf16(a[mi], b[nj], acc[mi][nj], 0, 0, 0);
        __builtin_amdgcn_s_setprio(0);
        const int t_ = b0; b0 = b1; b1 = b2; b2 = t_;
    }
    #undef STAGE

    #pragma unroll
    for (int mi = 0; mi < 8; ++mi) {
        #pragma unroll
        for (int j = 0; j < 4; ++j) {
            const int grow = tileM * 256 + wm * 128 + mi * 16 + q * 4 + j;
            if (grow < count) {
                const int token = tok_list[e * T_TOK + grow];
                const float gate = gate_list[e * T_TOK + grow];
                float* orow = out + (size_t)token * D_MODEL + tileN * 256 + wn * 64 + l15;
                #pragma unroll
                for (int nj = 0; nj < 4; ++nj)
                    atomicAdd(orow + nj * 16, gate * acc[mi][nj][j]);
            }
        }
    }
}

extern "C" void kernel_launch(void* const* d_in, const int* in_sizes, int n_in,
                              void* d_out, int out_size, void* d_ws, size_t ws_size,
                              hipStream_t stream)
{
    const float* x   = (const float*)d_in[0];   // [4096, 1024]
    const float* rw  = (const float*)d_in[1];   // [16, 1024]
    const float* wsw = (const float*)d_in[2];   // [16, 4096, 1024]
    const float* w2s = (const float*)d_in[3];   // [16, 1024, 2048]
    float* out = (float*)d_out;                 // [4096, 1024] fp32

    char* wsb = (char*)d_ws;
    int* counts      = (int*)wsb;                                  // 64 B
    int* prefix      = (int*)(wsb + 128);                          // 17 ints
    int* tok_list    = (int*)(wsb + 1024);                         // 256 KB
    float* gate_list = (float*)(wsb + 1024 + E_EXP * T_TOK * 4);   // 256 KB
    __bf16* x_bf     = (__bf16*)(wsb + (1u << 20));                // [1, 9) MB
    __bf16* act      = (__bf16*)(wsb + (12u << 20));               // [12, ~96) MB (256-padded rows)
    __bf16* ws_bf    = (__bf16*)(wsb + (96u << 20));               // [96, 230) MB
    __bf16* w2_bf    = ws_bf;                                      // aliased: rewritten after gemm1

    hipMemsetAsync(counts, 0, E_EXP * sizeof(int), stream);
    hipMemsetAsync(d_out, 0, (size_t)out_size * sizeof(float), stream);

    router_kernel<<<dim3(T_TOK / 4), 256, 0, stream>>>(x, rw, counts, tok_list, gate_list);
    prefix_kernel<<<1, 64, 0, stream>>>(counts, prefix);

    cvt_kernel<<<2048, 256, 0, stream>>>(x, x_bf, T_TOK * D_MODEL / 8);
    cvt_kernel<<<8192, 256, 0, stream>>>(wsw, ws_bf, E_EXP * 2 * I_DIM * D_MODEL / 8);

    gemm1_kernel<<<dim3(2048), 512, 0, stream>>>(
        x_bf, ws_bf, counts, prefix, tok_list, act);

    cvt_kernel<<<8192, 256, 0, stream>>>(w2s, w2_bf, E_EXP * D_MODEL * I_DIM / 8);

    gemm2_kernel<<<dim3(1024), 512, 0, stream>>>(
        act, w2_bf, counts, prefix, tok_list, gate_list, out);
}

// Round 7
// 665.853 us; speedup vs baseline: 1.1492x; 1.1492x over previous
//
#include <hip/hip_runtime.h>
#include <hip/hip_bf16.h>

#define T_TOK 4096
#define D_MODEL 1024
#define I_DIM 2048
#define E_EXP 16

typedef __bf16 bf16x8 __attribute__((ext_vector_type(8)));
typedef float f32x4 __attribute__((ext_vector_type(4)));

__device__ __forceinline__ bf16x8 pack8(f32x4 a, f32x4 b) {
    bf16x8 r;
    r[0] = (__bf16)a[0]; r[1] = (__bf16)a[1]; r[2] = (__bf16)a[2]; r[3] = (__bf16)a[3];
    r[4] = (__bf16)b[0]; r[5] = (__bf16)b[1]; r[6] = (__bf16)b[2]; r[7] = (__bf16)b[3];
    return r;
}

__device__ __forceinline__ void gl2lds(const __bf16* src, __bf16* dst) {
    __builtin_amdgcn_global_load_lds(
        (const __attribute__((address_space(1))) unsigned int*)src,
        (__attribute__((address_space(3))) unsigned int*)dst, 16, 0, 0);
}

__global__ __launch_bounds__(256) void cvt_kernel(
    const float* __restrict__ in, __bf16* __restrict__ out, int n8)
{
    const int stride = gridDim.x * 256;
    for (int i = blockIdx.x * 256 + threadIdx.x; i < n8; i += stride) {
        f32x4 a = ((const f32x4*)in)[i * 2];
        f32x4 b = ((const f32x4*)in)[i * 2 + 1];
        ((bf16x8*)out)[i] = pack8(a, b);
    }
}

// ---------------- Router: fp64-accum logits, top-4, softmax-over-top4 ----------------
__global__ __launch_bounds__(256) void router_kernel(
    const float* __restrict__ x, const float* __restrict__ rw,
    int* __restrict__ counts, int* __restrict__ tok_list, float* __restrict__ gate_list)
{
    const int wid = threadIdx.x >> 6, lane = threadIdx.x & 63;
    const int t = blockIdx.x * 4 + wid;
    const int e = lane & 15, part = lane >> 4;

    const float* xr = x + (size_t)t * D_MODEL + part * 256;
    const float* wr = rw + (size_t)e * D_MODEL + part * 256;
    double acc = 0.0;
    #pragma unroll 4
    for (int i = 0; i < 256; i += 4) {
        f32x4 xv = *(const f32x4*)(xr + i);
        f32x4 wv = *(const f32x4*)(wr + i);
        acc += (double)xv[0] * wv[0] + (double)xv[1] * wv[1]
             + (double)xv[2] * wv[2] + (double)xv[3] * wv[3];
    }
    acc += __shfl_xor(acc, 16, 64);
    acc += __shfl_xor(acc, 32, 64);

    __shared__ float logits[4][16];
    if (lane < 16) logits[wid][lane] = (float)acc;
    __syncthreads();

    if (lane == 0) {
        float l[16];
        #pragma unroll
        for (int i = 0; i < 16; i++) l[i] = logits[wid][i];
        int idx[4]; float val[4];
        unsigned taken = 0;
        for (int k = 0; k < 4; k++) {
            int best = 0; float bv = -1e30f;
            for (int i = 0; i < 16; i++)
                if (!((taken >> i) & 1) && l[i] > bv) { bv = l[i]; best = i; }
            idx[k] = best; val[k] = bv; taken |= (1u << best);
        }
        float m = val[0];
        float w[4], s = 0.f;
        for (int k = 0; k < 4; k++) { w[k] = __expf(val[k] - m); s += w[k]; }
        for (int k = 0; k < 4; k++) {
            int ee = idx[k];
            int slot = atomicAdd(&counts[ee], 1);
            tok_list[ee * T_TOK + slot] = t;
            gate_list[ee * T_TOK + slot] = w[k] / s;
        }
    }
}

__global__ void prefix_kernel(const int* __restrict__ counts, int* __restrict__ prefix) {
    if (threadIdx.x == 0) {
        int acc = 0;
        for (int e = 0; e < E_EXP; e++) { prefix[e] = acc; acc += (counts[e] + 255) & ~255; }
        prefix[E_EXP] = acc;
    }
}

// ======================= GEMM1 + SwiGLU (m97 structure) =======================
// 128 tok x 64 act-cols (128 B-rows: 64 w1 + 64 v1), BK=64, 4 waves (2Mx2N),
// SINGLE-buffered 32 KB LDS, 2 x __syncthreads per K-step, gl_lds staging,
// 3 blocks/CU via __launch_bounds__(256,3) — inter-block overlap hides drain.
// 16 tileM slots: covers 2048 tokens/expert (counts can exceed 1024!).
__global__ __launch_bounds__(256, 3) void gemm1_kernel(
    const __bf16* __restrict__ xb, const __bf16* __restrict__ wsb,
    const int* __restrict__ counts, const int* __restrict__ prefix,
    const int* __restrict__ tok_list, __bf16* __restrict__ act)
{
    const int q8 = gridDim.x >> 3;                     // 1024
    const int lid = (blockIdx.x & 7) * q8 + (blockIdx.x >> 3);
    const int e = lid >> 9;                            // 512 blocks / expert
    const int r = lid & 511;
    const int tileM = r & 15;                          // 0..15 (2048 tokens)
    const int tileN = r >> 4;                          // 0..31

    const int count = counts[e];
    if (tileM * 128 >= count) return;

    const int tid = threadIdx.x;
    const int lane = tid & 63, w = tid >> 6;
    const int l15 = lane & 15, q = lane >> 4, l7 = lane & 7;
    const int wm = w >> 1, wc = w & 1;

    __shared__ __bf16 As[128 * 64];
    __shared__ __bf16 Bs[128 * 64];

    // staging: wave w covers rows [w*32, w*32+32) of A and of B; 4 issues x 8 rows
    const int rl = lane >> 3;                  // row within 8-row issue group
    const int lc = (lane & 7) ^ rl;            // logical chunk (involution with row&7)
    const __bf16* ptrA[4]; const __bf16* ptrB[4];
    #pragma unroll
    for (int i = 0; i < 4; ++i) {
        int grow = tileM * 128 + w * 32 + i * 8 + rl;
        if (grow >= count) grow = count - 1;
        const int token = tok_list[e * T_TOK + grow];
        ptrA[i] = xb + (size_t)token * D_MODEL + lc * 8;
        const int sub = w * 32 + i * 8 + rl;   // 0..127; rows 0-63 w1, 64-127 v1
        const int gcol = (sub < 64) ? (tileN * 64 + sub) : (I_DIM + tileN * 64 + (sub - 64));
        ptrB[i] = wsb + ((size_t)e * 2 * I_DIM + gcol) * D_MODEL + lc * 8;
    }
    __bf16* dA = &As[w * 2048];
    __bf16* dB = &Bs[w * 2048];

    #define STAGE(koff) do { \
        _Pragma("unroll") \
        for (int i_ = 0; i_ < 4; ++i_) gl2lds(ptrA[i_] + (koff), dA + i_ * 512); \
        _Pragma("unroll") \
        for (int i_ = 0; i_ < 4; ++i_) gl2lds(ptrB[i_] + (koff), dB + i_ * 512); \
    } while (0)

    f32x4 acc[4][4];
    const f32x4 z = {0.f, 0.f, 0.f, 0.f};
    #pragma unroll
    for (int mi = 0; mi < 4; ++mi)
        #pragma unroll
        for (int nj = 0; nj < 4; ++nj) acc[mi][nj] = z;

    const int c0 = (q ^ l7) * 8, c1 = ((4 + q) ^ l7) * 8;
    const int aoff = (wm * 64 + l15) * 64;     // + mi*1024 + c
    const int boff = (wc * 32 + l15) * 64;     // w1: +nj*1024+c ; v1: +4096+nj*1024+c

    STAGE(0);
    for (int kt = 0; kt < 16; ++kt) {
        __syncthreads();                        // drains vmcnt: tile kt resident
        bf16x8 a0[4], a1[4], b0[4], b1[4];
        #pragma unroll
        for (int mi = 0; mi < 4; ++mi) {
            a0[mi] = *(const bf16x8*)&As[aoff + mi * 1024 + c0];
            a1[mi] = *(const bf16x8*)&As[aoff + mi * 1024 + c1];
        }
        #pragma unroll
        for (int nj = 0; nj < 2; ++nj) {
            b0[nj]     = *(const bf16x8*)&Bs[boff + nj * 1024 + c0];
            b0[nj + 2] = *(const bf16x8*)&Bs[boff + 4096 + nj * 1024 + c0];
            b1[nj]     = *(const bf16x8*)&Bs[boff + nj * 1024 + c1];
            b1[nj + 2] = *(const bf16x8*)&Bs[boff + 4096 + nj * 1024 + c1];
        }
        __syncthreads();                        // frags in regs: LDS free to overwrite
        if (kt + 1 < 16) STAGE((kt + 1) * 64);  // loads fly under the MFMAs
        #pragma unroll
        for (int mi = 0; mi < 4; ++mi)
            #pragma unroll
            for (int nj = 0; nj < 4; ++nj) {
                acc[mi][nj] = __builtin_amdgcn_mfma_f32_16x16x32_bf16(a0[mi], b0[nj], acc[mi][nj], 0, 0, 0);
                acc[mi][nj] = __builtin_amdgcn_mfma_f32_16x16x32_bf16(a1[mi], b1[nj], acc[mi][nj], 0, 0, 0);
            }
    }
    #undef STAGE

    const int abase = prefix[e];
    #pragma unroll
    for (int mi = 0; mi < 4; ++mi) {
        #pragma unroll
        for (int j = 0; j < 4; ++j) {
            const int grow = tileM * 128 + wm * 64 + mi * 16 + q * 4 + j;
            if (grow < count) {
                __bf16* arowp = act + (size_t)(abase + grow) * I_DIM + tileN * 64 + wc * 32 + l15;
                #pragma unroll
                for (int nj = 0; nj < 2; ++nj) {
                    const float v1 = acc[mi][nj][j];
                    const float v2 = acc[mi][nj + 2][j];
                    arowp[nj * 16] = (__bf16)(v1 / (1.f + __expf(-v1)) * v2);
                }
            }
        }
    }
}

// ======================= GEMM2 (m97 structure) =======================
// 128 rows x 128 d-cols, K=2048 split in 2 halves (h), BK=64, single-buffer,
// 3 blocks/CU; 16 tileM slots (2048 tokens/expert); atomics scatter gate*y.
__global__ __launch_bounds__(256, 3) void gemm2_kernel(
    const __bf16* __restrict__ act, const __bf16* __restrict__ w2b,
    const int* __restrict__ counts, const int* __restrict__ prefix,
    const int* __restrict__ tok_list, const float* __restrict__ gate_list,
    float* __restrict__ out)
{
    const int q8 = gridDim.x >> 3;                     // 512
    const int lid = (blockIdx.x & 7) * q8 + (blockIdx.x >> 3);
    const int e = lid >> 8;                            // 256 blocks / expert
    const int r = lid & 255;
    const int tileM = r & 15;                          // 0..15
    const int tileN = (r >> 4) & 7;                    // 0..7
    const int h = r >> 7;                              // 0..1

    const int count = counts[e];
    if (tileM * 128 >= count) return;

    const int tid = threadIdx.x;
    const int lane = tid & 63, w = tid >> 6;
    const int l15 = lane & 15, q = lane >> 4, l7 = lane & 7;
    const int wm = w >> 1, wc = w & 1;
    const int abase = prefix[e];

    __shared__ __bf16 As[128 * 64];
    __shared__ __bf16 Bs[128 * 64];

    const int rl = lane >> 3;
    const int lc = (lane & 7) ^ rl;
    const __bf16* ptrA[4]; const __bf16* ptrB[4];
    #pragma unroll
    for (int i = 0; i < 4; ++i) {
        const int ar = tileM * 128 + w * 32 + i * 8 + rl;      // padded rows exist in act
        ptrA[i] = act + (size_t)(abase + ar) * I_DIM + h * 1024 + lc * 8;
        const int dcol = tileN * 128 + w * 32 + i * 8 + rl;
        ptrB[i] = w2b + ((size_t)e * D_MODEL + dcol) * I_DIM + h * 1024 + lc * 8;
    }
    __bf16* dA = &As[w * 2048];
    __bf16* dB = &Bs[w * 2048];

    #define STAGE(koff) do { \
        _Pragma("unroll") \
        for (int i_ = 0; i_ < 4; ++i_) gl2lds(ptrA[i_] + (koff), dA + i_ * 512); \
        _Pragma("unroll") \
        for (int i_ = 0; i_ < 4; ++i_) gl2lds(ptrB[i_] + (koff), dB + i_ * 512); \
    } while (0)

    f32x4 acc[4][4];
    const f32x4 z = {0.f, 0.f, 0.f, 0.f};
    #pragma unroll
    for (int mi = 0; mi < 4; ++mi)
        #pragma unroll
        for (int nj = 0; nj < 4; ++nj) acc[mi][nj] = z;

    const int c0 = (q ^ l7) * 8, c1 = ((4 + q) ^ l7) * 8;
    const int aoff = (wm * 64 + l15) * 64;     // + mi*1024 + c
    const int boff = (wc * 64 + l15) * 64;     // + nj*1024 + c

    STAGE(0);
    for (int kt = 0; kt < 16; ++kt) {
        __syncthreads();
        bf16x8 a0[4], a1[4], b0[4], b1[4];
        #pragma unroll
        for (int mi = 0; mi < 4; ++mi) {
            a0[mi] = *(const bf16x8*)&As[aoff + mi * 1024 + c0];
            a1[mi] = *(const bf16x8*)&As[aoff + mi * 1024 + c1];
        }
        #pragma unroll
        for (int nj = 0; nj < 4; ++nj) {
            b0[nj] = *(const bf16x8*)&Bs[boff + nj * 1024 + c0];
            b1[nj] = *(const bf16x8*)&Bs[boff + nj * 1024 + c1];
        }
        __syncthreads();
        if (kt + 1 < 16) STAGE((kt + 1) * 64);
        #pragma unroll
        for (int mi = 0; mi < 4; ++mi)
            #pragma unroll
            for (int nj = 0; nj < 4; ++nj) {
                acc[mi][nj] = __builtin_amdgcn_mfma_f32_16x16x32_bf16(a0[mi], b0[nj], acc[mi][nj], 0, 0, 0);
                acc[mi][nj] = __builtin_amdgcn_mfma_f32_16x16x32_bf16(a1[mi], b1[nj], acc[mi][nj], 0, 0, 0);
            }
    }
    #undef STAGE

    #pragma unroll
    for (int mi = 0; mi < 4; ++mi) {
        #pragma unroll
        for (int j = 0; j < 4; ++j) {
            const int grow = tileM * 128 + wm * 64 + mi * 16 + q * 4 + j;
            if (grow < count) {
                const int token = tok_list[e * T_TOK + grow];
                const float gate = gate_list[e * T_TOK + grow];
                float* orow = out + (size_t)token * D_MODEL + tileN * 128 + wc * 64 + l15;
                #pragma unroll
                for (int nj = 0; nj < 4; ++nj)
                    atomicAdd(orow + nj * 16, gate * acc[mi][nj][j]);
            }
        }
    }
}

extern "C" void kernel_launch(void* const* d_in, const int* in_sizes, int n_in,
                              void* d_out, int out_size, void* d_ws, size_t ws_size,
                              hipStream_t stream)
{
    const float* x   = (const float*)d_in[0];   // [4096, 1024]
    const float* rw  = (const float*)d_in[1];   // [16, 1024]
    const float* wsw = (const float*)d_in[2];   // [16, 4096, 1024]
    const float* w2s = (const float*)d_in[3];   // [16, 1024, 2048]
    float* out = (float*)d_out;                 // [4096, 1024] fp32

    char* wsb = (char*)d_ws;
    int* counts      = (int*)wsb;                                  // 64 B
    int* prefix      = (int*)(wsb + 128);                          // 17 ints
    int* tok_list    = (int*)(wsb + 1024);                         // 256 KB
    float* gate_list = (float*)(wsb + 1024 + E_EXP * T_TOK * 4);   // 256 KB
    __bf16* x_bf     = (__bf16*)(wsb + (1u << 20));                // [1, 9) MB
    __bf16* act      = (__bf16*)(wsb + (12u << 20));               // [12, ~96) MB (256-padded rows)
    __bf16* ws_bf    = (__bf16*)(wsb + (96u << 20));               // [96, 231) MB
    __bf16* w2_bf    = ws_bf;                                      // aliased: rewritten after gemm1

    hipMemsetAsync(counts, 0, E_EXP * sizeof(int), stream);
    hipMemsetAsync(d_out, 0, (size_t)out_size * sizeof(float), stream);

    router_kernel<<<dim3(T_TOK / 4), 256, 0, stream>>>(x, rw, counts, tok_list, gate_list);
    prefix_kernel<<<1, 64, 0, stream>>>(counts, prefix);

    cvt_kernel<<<2048, 256, 0, stream>>>(x, x_bf, T_TOK * D_MODEL / 8);
    cvt_kernel<<<8192, 256, 0, stream>>>(wsw, ws_bf, E_EXP * 2 * I_DIM * D_MODEL / 8);

    gemm1_kernel<<<dim3(8192), 256, 0, stream>>>(
        x_bf, ws_bf, counts, prefix, tok_list, act);

    cvt_kernel<<<8192, 256, 0, stream>>>(w2s, w2_bf, E_EXP * D_MODEL * I_DIM / 8);

    gemm2_kernel<<<dim3(4096), 256, 0, stream>>>(
        act, w2_bf, counts, prefix, tok_list, gate_list, out);
}

// Round 8
// 500.607 us; speedup vs baseline: 1.5285x; 1.3301x over previous
//
#include <hip/hip_runtime.h>
#include <hip/hip_bf16.h>

#define T_TOK 4096
#define D_MODEL 1024
#define I_DIM 2048
#define E_EXP 16

typedef __bf16 bf16x8 __attribute__((ext_vector_type(8)));
typedef float f32x4 __attribute__((ext_vector_type(4)));

__device__ __forceinline__ bf16x8 pack8(f32x4 a, f32x4 b) {
    bf16x8 r;
    r[0] = (__bf16)a[0]; r[1] = (__bf16)a[1]; r[2] = (__bf16)a[2]; r[3] = (__bf16)a[3];
    r[4] = (__bf16)b[0]; r[5] = (__bf16)b[1]; r[6] = (__bf16)b[2]; r[7] = (__bf16)b[3];
    return r;
}

__device__ __forceinline__ void gl2lds(const __bf16* src, __bf16* dst) {
    __builtin_amdgcn_global_load_lds(
        (const __attribute__((address_space(1))) unsigned int*)src,
        (__attribute__((address_space(3))) unsigned int*)dst, 16, 0, 0);
}

__global__ __launch_bounds__(256) void cvt_kernel(
    const float* __restrict__ in, __bf16* __restrict__ out, int n8)
{
    const int stride = gridDim.x * 256;
    for (int i = blockIdx.x * 256 + threadIdx.x; i < n8; i += stride) {
        f32x4 a = ((const f32x4*)in)[i * 2];
        f32x4 b = ((const f32x4*)in)[i * 2 + 1];
        ((bf16x8*)out)[i] = pack8(a, b);
    }
}

// ---------------- Router phase 1: fp64-accum logits, top-4, softmax-over-top4.
// NO atomics: writes packed expert choices (4x4 bits) + float4 gates per token.
__global__ __launch_bounds__(256) void router_topk_kernel(
    const float* __restrict__ x, const float* __restrict__ rw,
    unsigned int* __restrict__ choices, float* __restrict__ gate4)
{
    const int wid = threadIdx.x >> 6, lane = threadIdx.x & 63;
    const int t = blockIdx.x * 4 + wid;
    const int e = lane & 15, part = lane >> 4;

    const float* xr = x + (size_t)t * D_MODEL + part * 256;
    const float* wr = rw + (size_t)e * D_MODEL + part * 256;
    double acc = 0.0;
    #pragma unroll 4
    for (int i = 0; i < 256; i += 4) {
        f32x4 xv = *(const f32x4*)(xr + i);
        f32x4 wv = *(const f32x4*)(wr + i);
        acc += (double)xv[0] * wv[0] + (double)xv[1] * wv[1]
             + (double)xv[2] * wv[2] + (double)xv[3] * wv[3];
    }
    acc += __shfl_xor(acc, 16, 64);
    acc += __shfl_xor(acc, 32, 64);

    __shared__ float logits[4][16];
    if (lane < 16) logits[wid][lane] = (float)acc;
    __syncthreads();

    if (lane == 0) {
        float l[16];
        #pragma unroll
        for (int i = 0; i < 16; i++) l[i] = logits[wid][i];
        int idx[4]; float val[4];
        unsigned taken = 0;
        for (int k = 0; k < 4; k++) {
            int best = 0; float bv = -1e30f;
            for (int i = 0; i < 16; i++)
                if (!((taken >> i) & 1) && l[i] > bv) { bv = l[i]; best = i; }
            idx[k] = best; val[k] = bv; taken |= (1u << best);
        }
        const float m = val[0];
        float w[4], s = 0.f;
        for (int k = 0; k < 4; k++) { w[k] = __expf(val[k] - m); s += w[k]; }
        choices[t] = (unsigned)idx[0] | ((unsigned)idx[1] << 4)
                   | ((unsigned)idx[2] << 8) | ((unsigned)idx[3] << 12);
        f32x4 g = {w[0] / s, w[1] / s, w[2] / s, w[3] / s};
        *(f32x4*)(gate4 + t * 4) = g;
    }
}

// ---------------- Router phase 2: per-expert list build via ballot prefix sums.
// 16 blocks (one per expert); token-ordered, deterministic, no contended atomics.
__global__ __launch_bounds__(256) void build_lists_kernel(
    const unsigned int* __restrict__ choices, const float* __restrict__ gate4,
    int* __restrict__ counts, int* __restrict__ tok_list, float* __restrict__ gate_list)
{
    const int e = blockIdx.x;
    const int tid = threadIdx.x, lane = tid & 63, w = tid >> 6;
    __shared__ int wave_cnt[4];
    __shared__ int running;
    if (tid == 0) running = 0;
    __syncthreads();
    for (int chunk = 0; chunk < T_TOK; chunk += 256) {
        const int t = chunk + tid;
        const unsigned int ch = choices[t];
        int k = -1;
        #pragma unroll
        for (int kk = 0; kk < 4; ++kk)
            if (((ch >> (4 * kk)) & 15u) == (unsigned)e) k = kk;
        const unsigned long long m = __ballot(k >= 0);
        const int my = __popcll(m & ((1ull << lane) - 1ull));
        if (lane == 0) wave_cnt[w] = __popcll(m);
        __syncthreads();
        int base = running;
        #pragma unroll
        for (int i = 0; i < 4; ++i) if (i < w) base += wave_cnt[i];
        if (k >= 0) {
            const int slot = base + my;
            tok_list[e * T_TOK + slot] = t;
            gate_list[e * T_TOK + slot] = gate4[t * 4 + k];
        }
        __syncthreads();
        if (tid == 0) running += wave_cnt[0] + wave_cnt[1] + wave_cnt[2] + wave_cnt[3];
        __syncthreads();
    }
    if (tid == 0) counts[e] = running;
}

__global__ void prefix_kernel(const int* __restrict__ counts, int* __restrict__ prefix) {
    if (threadIdx.x == 0) {
        int acc = 0;
        for (int e = 0; e < E_EXP; e++) { prefix[e] = acc; acc += (counts[e] + 255) & ~255; }
        prefix[E_EXP] = acc;
    }
}

// ======================= GEMM1 + SwiGLU (m97 structure) =======================
// 128 tok x 64 act-cols (128 B-rows: 64 w1 + 64 v1), BK=64, 4 waves (2Mx2N),
// SINGLE-buffered 32 KB LDS, 2 x __syncthreads per K-step, gl_lds staging,
// 3 blocks/CU via __launch_bounds__(256,3) — inter-block overlap hides drain.
// 16 tileM slots: covers 2048 tokens/expert (counts can exceed 1024!).
__global__ __launch_bounds__(256, 3) void gemm1_kernel(
    const __bf16* __restrict__ xb, const __bf16* __restrict__ wsb,
    const int* __restrict__ counts, const int* __restrict__ prefix,
    const int* __restrict__ tok_list, __bf16* __restrict__ act)
{
    const int q8 = gridDim.x >> 3;                     // 1024
    const int lid = (blockIdx.x & 7) * q8 + (blockIdx.x >> 3);
    const int e = lid >> 9;                            // 512 blocks / expert
    const int r = lid & 511;
    const int tileM = r & 15;                          // 0..15 (2048 tokens)
    const int tileN = r >> 4;                          // 0..31

    const int count = counts[e];
    if (tileM * 128 >= count) return;

    const int tid = threadIdx.x;
    const int lane = tid & 63, w = tid >> 6;
    const int l15 = lane & 15, q = lane >> 4, l7 = lane & 7;
    const int wm = w >> 1, wc = w & 1;

    __shared__ __bf16 As[128 * 64];
    __shared__ __bf16 Bs[128 * 64];

    // staging: wave w covers rows [w*32, w*32+32) of A and of B; 4 issues x 8 rows
    const int rl = lane >> 3;                  // row within 8-row issue group
    const int lc = (lane & 7) ^ rl;            // logical chunk (involution with row&7)
    const __bf16* ptrA[4]; const __bf16* ptrB[4];
    #pragma unroll
    for (int i = 0; i < 4; ++i) {
        int grow = tileM * 128 + w * 32 + i * 8 + rl;
        if (grow >= count) grow = count - 1;
        const int token = tok_list[e * T_TOK + grow];
        ptrA[i] = xb + (size_t)token * D_MODEL + lc * 8;
        const int sub = w * 32 + i * 8 + rl;   // 0..127; rows 0-63 w1, 64-127 v1
        const int gcol = (sub < 64) ? (tileN * 64 + sub) : (I_DIM + tileN * 64 + (sub - 64));
        ptrB[i] = wsb + ((size_t)e * 2 * I_DIM + gcol) * D_MODEL + lc * 8;
    }
    __bf16* dA = &As[w * 2048];
    __bf16* dB = &Bs[w * 2048];

    #define STAGE(koff) do { \
        _Pragma("unroll") \
        for (int i_ = 0; i_ < 4; ++i_) gl2lds(ptrA[i_] + (koff), dA + i_ * 512); \
        _Pragma("unroll") \
        for (int i_ = 0; i_ < 4; ++i_) gl2lds(ptrB[i_] + (koff), dB + i_ * 512); \
    } while (0)

    f32x4 acc[4][4];
    const f32x4 z = {0.f, 0.f, 0.f, 0.f};
    #pragma unroll
    for (int mi = 0; mi < 4; ++mi)
        #pragma unroll
        for (int nj = 0; nj < 4; ++nj) acc[mi][nj] = z;

    const int c0 = (q ^ l7) * 8, c1 = ((4 + q) ^ l7) * 8;
    const int aoff = (wm * 64 + l15) * 64;     // + mi*1024 + c
    const int boff = (wc * 32 + l15) * 64;     // w1: +nj*1024+c ; v1: +4096+nj*1024+c

    STAGE(0);
    for (int kt = 0; kt < 16; ++kt) {
        __syncthreads();                        // drains vmcnt: tile kt resident
        bf16x8 a0[4], a1[4], b0[4], b1[4];
        #pragma unroll
        for (int mi = 0; mi < 4; ++mi) {
            a0[mi] = *(const bf16x8*)&As[aoff + mi * 1024 + c0];
            a1[mi] = *(const bf16x8*)&As[aoff + mi * 1024 + c1];
        }
        #pragma unroll
        for (int nj = 0; nj < 2; ++nj) {
            b0[nj]     = *(const bf16x8*)&Bs[boff + nj * 1024 + c0];
            b0[nj + 2] = *(const bf16x8*)&Bs[boff + 4096 + nj * 1024 + c0];
            b1[nj]     = *(const bf16x8*)&Bs[boff + nj * 1024 + c1];
            b1[nj + 2] = *(const bf16x8*)&Bs[boff + 4096 + nj * 1024 + c1];
        }
        __syncthreads();                        // frags in regs: LDS free to overwrite
        if (kt + 1 < 16) STAGE((kt + 1) * 64);  // loads fly under the MFMAs
        #pragma unroll
        for (int mi = 0; mi < 4; ++mi)
            #pragma unroll
            for (int nj = 0; nj < 4; ++nj) {
                acc[mi][nj] = __builtin_amdgcn_mfma_f32_16x16x32_bf16(a0[mi], b0[nj], acc[mi][nj], 0, 0, 0);
                acc[mi][nj] = __builtin_amdgcn_mfma_f32_16x16x32_bf16(a1[mi], b1[nj], acc[mi][nj], 0, 0, 0);
            }
    }
    #undef STAGE

    const int abase = prefix[e];
    #pragma unroll
    for (int mi = 0; mi < 4; ++mi) {
        #pragma unroll
        for (int j = 0; j < 4; ++j) {
            const int grow = tileM * 128 + wm * 64 + mi * 16 + q * 4 + j;
            if (grow < count) {
                __bf16* arowp = act + (size_t)(abase + grow) * I_DIM + tileN * 64 + wc * 32 + l15;
                #pragma unroll
                for (int nj = 0; nj < 2; ++nj) {
                    const float v1 = acc[mi][nj][j];
                    const float v2 = acc[mi][nj + 2][j];
                    arowp[nj * 16] = (__bf16)(v1 / (1.f + __expf(-v1)) * v2);
                }
            }
        }
    }
}

// ======================= GEMM2 (m97 structure) =======================
// 128 rows x 128 d-cols, K=2048 split in 2 halves (h), BK=64, single-buffer,
// 3 blocks/CU; 16 tileM slots (2048 tokens/expert); atomics scatter gate*y.
__global__ __launch_bounds__(256, 3) void gemm2_kernel(
    const __bf16* __restrict__ act, const __bf16* __restrict__ w2b,
    const int* __restrict__ counts, const int* __restrict__ prefix,
    const int* __restrict__ tok_list, const float* __restrict__ gate_list,
    float* __restrict__ out)
{
    const int q8 = gridDim.x >> 3;                     // 512
    const int lid = (blockIdx.x & 7) * q8 + (blockIdx.x >> 3);
    const int e = lid >> 8;                            // 256 blocks / expert
    const int r = lid & 255;
    const int tileM = r & 15;                          // 0..15
    const int tileN = (r >> 4) & 7;                    // 0..7
    const int h = r >> 7;                              // 0..1

    const int count = counts[e];
    if (tileM * 128 >= count) return;

    const int tid = threadIdx.x;
    const int lane = tid & 63, w = tid >> 6;
    const int l15 = lane & 15, q = lane >> 4, l7 = lane & 7;
    const int wm = w >> 1, wc = w & 1;
    const int abase = prefix[e];

    __shared__ __bf16 As[128 * 64];
    __shared__ __bf16 Bs[128 * 64];

    const int rl = lane >> 3;
    const int lc = (lane & 7) ^ rl;
    const __bf16* ptrA[4]; const __bf16* ptrB[4];
    #pragma unroll
    for (int i = 0; i < 4; ++i) {
        const int ar = tileM * 128 + w * 32 + i * 8 + rl;      // padded rows exist in act
        ptrA[i] = act + (size_t)(abase + ar) * I_DIM + h * 1024 + lc * 8;
        const int dcol = tileN * 128 + w * 32 + i * 8 + rl;
        ptrB[i] = w2b + ((size_t)e * D_MODEL + dcol) * I_DIM + h * 1024 + lc * 8;
    }
    __bf16* dA = &As[w * 2048];
    __bf16* dB = &Bs[w * 2048];

    #define STAGE(koff) do { \
        _Pragma("unroll") \
        for (int i_ = 0; i_ < 4; ++i_) gl2lds(ptrA[i_] + (koff), dA + i_ * 512); \
        _Pragma("unroll") \
        for (int i_ = 0; i_ < 4; ++i_) gl2lds(ptrB[i_] + (koff), dB + i_ * 512); \
    } while (0)

    f32x4 acc[4][4];
    const f32x4 z = {0.f, 0.f, 0.f, 0.f};
    #pragma unroll
    for (int mi = 0; mi < 4; ++mi)
        #pragma unroll
        for (int nj = 0; nj < 4; ++nj) acc[mi][nj] = z;

    const int c0 = (q ^ l7) * 8, c1 = ((4 + q) ^ l7) * 8;
    const int aoff = (wm * 64 + l15) * 64;     // + mi*1024 + c
    const int boff = (wc * 64 + l15) * 64;     // + nj*1024 + c

    STAGE(0);
    for (int kt = 0; kt < 16; ++kt) {
        __syncthreads();
        bf16x8 a0[4], a1[4], b0[4], b1[4];
        #pragma unroll
        for (int mi = 0; mi < 4; ++mi) {
            a0[mi] = *(const bf16x8*)&As[aoff + mi * 1024 + c0];
            a1[mi] = *(const bf16x8*)&As[aoff + mi * 1024 + c1];
        }
        #pragma unroll
        for (int nj = 0; nj < 4; ++nj) {
            b0[nj] = *(const bf16x8*)&Bs[boff + nj * 1024 + c0];
            b1[nj] = *(const bf16x8*)&Bs[boff + nj * 1024 + c1];
        }
        __syncthreads();
        if (kt + 1 < 16) STAGE((kt + 1) * 64);
        #pragma unroll
        for (int mi = 0; mi < 4; ++mi)
            #pragma unroll
            for (int nj = 0; nj < 4; ++nj) {
                acc[mi][nj] = __builtin_amdgcn_mfma_f32_16x16x32_bf16(a0[mi], b0[nj], acc[mi][nj], 0, 0, 0);
                acc[mi][nj] = __builtin_amdgcn_mfma_f32_16x16x32_bf16(a1[mi], b1[nj], acc[mi][nj], 0, 0, 0);
            }
    }
    #undef STAGE

    #pragma unroll
    for (int mi = 0; mi < 4; ++mi) {
        #pragma unroll
        for (int j = 0; j < 4; ++j) {
            const int grow = tileM * 128 + wm * 64 + mi * 16 + q * 4 + j;
            if (grow < count) {
                const int token = tok_list[e * T_TOK + grow];
                const float gate = gate_list[e * T_TOK + grow];
                float* orow = out + (size_t)token * D_MODEL + tileN * 128 + wc * 64 + l15;
                #pragma unroll
                for (int nj = 0; nj < 4; ++nj)
                    atomicAdd(orow + nj * 16, gate * acc[mi][nj][j]);
            }
        }
    }
}

extern "C" void kernel_launch(void* const* d_in, const int* in_sizes, int n_in,
                              void* d_out, int out_size, void* d_ws, size_t ws_size,
                              hipStream_t stream)
{
    const float* x   = (const float*)d_in[0];   // [4096, 1024]
    const float* rw  = (const float*)d_in[1];   // [16, 1024]
    const float* wsw = (const float*)d_in[2];   // [16, 4096, 1024]
    const float* w2s = (const float*)d_in[3];   // [16, 1024, 2048]
    float* out = (float*)d_out;                 // [4096, 1024] fp32

    char* wsb = (char*)d_ws;
    int* counts        = (int*)wsb;                                  // 64 B
    int* prefix        = (int*)(wsb + 128);                          // 17 ints
    int* tok_list      = (int*)(wsb + 1024);                         // 256 KB
    float* gate_list   = (float*)(wsb + 1024 + E_EXP * T_TOK * 4);   // 256 KB
    unsigned* choices  = (unsigned*)(wsb + 544u * 1024);             // 16 KB
    float* gate4       = (float*)(wsb + 576u * 1024);                // 64 KB
    __bf16* x_bf       = (__bf16*)(wsb + (1u << 20));                // [1, 9) MB
    __bf16* act        = (__bf16*)(wsb + (12u << 20));               // [12, ~96) MB (256-padded rows)
    __bf16* ws_bf      = (__bf16*)(wsb + (96u << 20));               // [96, 231) MB
    __bf16* w2_bf      = ws_bf;                                      // aliased: rewritten after gemm1

    hipMemsetAsync(d_out, 0, (size_t)out_size * sizeof(float), stream);

    router_topk_kernel<<<dim3(T_TOK / 4), 256, 0, stream>>>(x, rw, choices, gate4);
    build_lists_kernel<<<dim3(E_EXP), 256, 0, stream>>>(choices, gate4, counts, tok_list, gate_list);
    prefix_kernel<<<1, 64, 0, stream>>>(counts, prefix);

    cvt_kernel<<<2048, 256, 0, stream>>>(x, x_bf, T_TOK * D_MODEL / 8);
    cvt_kernel<<<8192, 256, 0, stream>>>(wsw, ws_bf, E_EXP * 2 * I_DIM * D_MODEL / 8);

    gemm1_kernel<<<dim3(8192), 256, 0, stream>>>(
        x_bf, ws_bf, counts, prefix, tok_list, act);

    cvt_kernel<<<8192, 256, 0, stream>>>(w2s, w2_bf, E_EXP * D_MODEL * I_DIM / 8);

    gemm2_kernel<<<dim3(4096), 256, 0, stream>>>(
        act, w2_bf, counts, prefix, tok_list, gate_list, out);
}